// Round 3
// baseline (500.561 us; speedup 1.0000x reference)
//
#include <hip/hip_runtime.h>
#include <hip/hip_bf16.h>

#define L_SEQ 40
#define B_SZ  16
#define V_SZ  10000
#define V_PAD 10240
#define NPAIR 780
#define NROWP 784                 // 780 pairs + 1 init row + 3 pad "pairs"
#define M_ROWS (NROWP * B_SZ)     // 12544 rows = 196 strips of 64

typedef __attribute__((ext_vector_type(8))) short short8;
typedef __attribute__((ext_vector_type(4))) float f32x4;

__device__ __forceinline__ unsigned short f2bf(float f) {
    unsigned int u = __float_as_uint(f);
    unsigned int r = u + 0x7FFFu + ((u >> 16) & 1u);
    return (unsigned short)(r >> 16);
}

// ---------------------------------------------------------------------------
// K1: fused prep. blocks [0,2560): transpose Ww2 -> WwT(fp32)/WbT(bf16);
//     blocks [2560,2880): UV = h @ {Wt1,Ww1} halves; blocks [2880,..): zero rowsum
// ---------------------------------------------------------------------------
__global__ __launch_bounds__(256) void prep_kernel(
        const float* __restrict__ Ww2, float* __restrict__ WwT,
        unsigned short* __restrict__ WbT,
        const float* __restrict__ h, const float* __restrict__ Wt1,
        const float* __restrict__ Ww1, float* __restrict__ UV,
        float* __restrict__ rowsum) {
    const int bx = blockIdx.x;
    const int t = threadIdx.x;
    __shared__ float tile[32][33];
    __shared__ float hs[8 * 512];
    if (bx < 2560) {
        // ---- transpose Ww2 [256,10000] -> [10240,256] (fp32 + bf16) ----
        int v0 = (bx % 320) * 32;
        int k0 = (bx / 320) * 32;
        int tx = t & 31, ty = t >> 5;   // 32 x 8
#pragma unroll
        for (int r = 0; r < 4; r++) {
            int k = k0 + ty + r * 8;
            int v = v0 + tx;
            tile[ty + r * 8][tx] = (v < V_SZ) ? Ww2[k * V_SZ + v] : 0.0f;
        }
        __syncthreads();
#pragma unroll
        for (int r = 0; r < 4; r++) {
            int vrow = ty + r * 8;
            float val = tile[tx][vrow];
            int out_idx = (v0 + vrow) * 256 + (k0 + tx);
            WwT[out_idx] = val;
            WbT[out_idx] = f2bf(val);
        }
    } else if (bx < 2880) {
        // ---- UV gemm: h[640,512] @ W[512,256] x4 ----
        int ub = bx - 2560;
        int which = ub / 80;         // 0:Ut 1:Vt 2:Uw 3:Vw
        int m0 = (ub % 80) * 8;
        const float4* src = (const float4*)(h + (size_t)m0 * 512);
        float4* dst4 = (float4*)hs;
#pragma unroll
        for (int v = 0; v < 4; v++) dst4[v * 256 + t] = src[v * 256 + t];
        __syncthreads();
        const float* W = ((which < 2) ? Wt1 : Ww1) + ((which & 1) ? 512 * 256 : 0);
        float acc[8] = {};
        for (int f = 0; f < 512; f += 4) {
            float w0 = W[(f + 0) * 256 + t];
            float w1 = W[(f + 1) * 256 + t];
            float w2 = W[(f + 2) * 256 + t];
            float w3 = W[(f + 3) * 256 + t];
#pragma unroll
            for (int r = 0; r < 8; r++) {
                acc[r] += hs[r * 512 + f] * w0 + hs[r * 512 + f + 1] * w1
                        + hs[r * 512 + f + 2] * w2 + hs[r * 512 + f + 3] * w3;
            }
        }
        float* dst = UV + ((size_t)which * 640 + m0) * 256;
#pragma unroll
        for (int r = 0; r < 8; r++) dst[r * 256 + t] = acc[r];
    } else {
        int idx = (bx - 2880) * 256 + t;
        if (idx < M_ROWS) rowsum[idx] = 0.0f;
    }
}

// ---------------------------------------------------------------------------
// K2: per (pair,b) row: X=tanh(Uw[i]+Vw[j]+bw1) (bf16), tlog/glog fp32 exact.
// One wave per row; p==780 is the init cell (i=j=0).
// ---------------------------------------------------------------------------
__global__ void build_rows(const float* __restrict__ UV,
                           const int* __restrict__ sentence,
                           const float* __restrict__ bt1,
                           const float* __restrict__ bw1,
                           const float* __restrict__ Wt2,
                           const float* __restrict__ bt2,
                           const float* __restrict__ WwT,
                           const float* __restrict__ bw2,
                           unsigned short* __restrict__ X,
                           float* __restrict__ tlog,
                           float* __restrict__ glog) {
    int w = blockIdx.x * 4 + (threadIdx.x >> 6);
    int lane = threadIdx.x & 63;
    int p = w >> 4, b = w & 15;
    int i = 0, j = 0;
    if (p < NPAIR) {
        int rem = p, len = L_SEQ - 1;
        while (rem >= len) { rem -= len; len--; i++; }
        j = i + 1 + rem;
    }
    int j1 = (j + 1 < L_SEQ) ? j + 1 : L_SEQ - 1;
    int tgt = sentence[j1 * B_SZ + b];
    const float* ut = UV + 0 * 640 * 256 + (i * B_SZ + b) * 256;
    const float* vt = UV + 1 * 640 * 256 + (j * B_SZ + b) * 256;
    const float* uw = UV + 2 * 640 * 256 + (i * B_SZ + b) * 256;
    const float* vw = UV + 3 * 640 * 256 + (j * B_SZ + b) * 256;
    const float* wcol = WwT + (size_t)tgt * 256;
    float td = 0.f, gd = 0.f;
#pragma unroll
    for (int q = 0; q < 4; q++) {
        int k = q * 64 + lane;
        float xt = tanhf(ut[k] + vt[k] + bt1[k]);
        float xw = tanhf(uw[k] + vw[k] + bw1[k]);
        td += xt * Wt2[k];
        gd += xw * wcol[k];
        X[(size_t)w * 256 + k] = f2bf(xw);
    }
#pragma unroll
    for (int off = 32; off >= 1; off >>= 1) {
        td += __shfl_xor(td, off);
        gd += __shfl_xor(gd, off);
    }
    if (lane == 0) {
        tlog[w] = td + bt2[0];
        glog[w] = gd + bw2[tgt];
    }
}

// ---------------------------------------------------------------------------
// K3: B-stationary GEMM + sum-exp.
// Grid (40 col-blocks, 14 row-groups), 4 waves/block. Each wave holds its
// 64-col x 256-K B panel in 128 VGPRs (loaded once). A streams as 64-row
// strips through a 2x32KB LDS double buffer (global_load_lds w=16, XOR
// granule swizzle). Inner loop: zero global loads, 8 k-steps x 16 MFMA.
// Epilogue per strip: exp(acc+bias) (bias=-inf kills pad cols), 16-lane
// butterfly, 16 atomics/wave.
// ---------------------------------------------------------------------------
__global__ __launch_bounds__(256, 2) void big_gemm(
        const unsigned short* __restrict__ X,
        const unsigned short* __restrict__ WbT,
        const float* __restrict__ bw2,
        float* __restrict__ rowsum) {
    __shared__ short As[2][64 * 256];   // 64 KB
    const int t = threadIdx.x;
    const int wid = t >> 6;
    const int lane = t & 63;
    const int l15 = lane & 15, l4 = lane >> 4;
    const int cwave0 = blockIdx.x * 256 + wid * 64;
    const int rg = blockIdx.y;
    const float NEGINF = -__builtin_inff();

    // ---- B panel into registers (once) ----
    short8 barr[8][4];
#pragma unroll
    for (int kk = 0; kk < 8; kk++)
#pragma unroll
        for (int ni = 0; ni < 4; ni++)
            barr[kk][ni] = *(const short8*)(WbT
                + (size_t)(cwave0 + ni * 16 + l15) * 256 + kk * 32 + l4 * 8);
    float bias[4];
#pragma unroll
    for (int ni = 0; ni < 4; ni++) {
        int col = cwave0 + ni * 16 + l15;
        bias[ni] = (col < V_SZ) ? bw2[col] : NEGINF;   // exp(x-inf)=0 for pads
    }

    auto dma_strip = [&](int buf, int strip) {
        const char* Xg = (const char*)(X + (size_t)strip * 64 * 256);
#pragma unroll
        for (int q = 0; q < 8; q++) {
            int flat = (wid * 8 + q) * 1024;
            int flatL = flat + lane * 16;
            int r = flatL >> 9;                  // dest row (512B/row)
            int sg = (flatL >> 4) & 31;          // dest granule
            int cg = sg ^ (r & 7);               // swizzled source granule
            __builtin_amdgcn_global_load_lds(
                (const __attribute__((address_space(1))) unsigned int*)(Xg + (r << 9) + (cg << 4)),
                (__attribute__((address_space(3))) unsigned int*)((char*)&As[buf][0] + flat),
                16, 0, 0);
        }
    };

    const int strip0 = rg * 14;
    const int xorv = l15 & 7;
    dma_strip(0, strip0);
    __syncthreads();

#pragma unroll 1
    for (int s = 0; s < 14; s++) {
        if (s < 13) dma_strip((s + 1) & 1, strip0 + s + 1);
        const short* Ab = &As[s & 1][0];
        f32x4 acc[4][4] = {};
#pragma unroll
        for (int kk = 0; kk < 8; kk++) {
            short8 a[4];
#pragma unroll
            for (int mi = 0; mi < 4; mi++) {
                int idx = (mi * 16 + l15) * 256 + (((kk * 4 + l4) ^ xorv) << 3);
                a[mi] = *(const short8*)(Ab + idx);
            }
#pragma unroll
            for (int mi = 0; mi < 4; mi++)
#pragma unroll
                for (int ni = 0; ni < 4; ni++)
                    acc[mi][ni] = __builtin_amdgcn_mfma_f32_16x16x32_bf16(
                        a[mi], barr[kk][ni], acc[mi][ni], 0, 0, 0);
        }
        __syncthreads();   // all waves done reading As[s&1]; next DMA may reuse it
        // ---- epilogue: exp + 16-lane butterfly + atomics ----
        int rbase = (strip0 + s) * 64;
#pragma unroll
        for (int mi = 0; mi < 4; mi++)
#pragma unroll
            for (int r = 0; r < 4; r++) {
                float v = __expf(acc[mi][0][r] + bias[0])
                        + __expf(acc[mi][1][r] + bias[1])
                        + __expf(acc[mi][2][r] + bias[2])
                        + __expf(acc[mi][3][r] + bias[3]);
#pragma unroll
                for (int off = 1; off < 16; off <<= 1) v += __shfl_xor(v, off);
                if (l15 == 0) atomicAdd(&rowsum[rbase + mi * 16 + l4 * 4 + r], v);
            }
    }
}

// ---------------------------------------------------------------------------
// K4: build tables in LDS + CKY DP. 16 blocks (one per batch), 512 thr.
// ---------------------------------------------------------------------------
__global__ __launch_bounds__(512) void dp_kernel(const float* __restrict__ tlog,
                          const float* __restrict__ glog,
                          const float* __restrict__ rowsum,
                          float* __restrict__ out) {
    __shared__ float Tl[1600], SHWl[1600], REl[1600];
    const int t = threadIdx.x;
    const int b = blockIdx.x;
    const float NEGINF = -__builtin_inff();
    for (int idx = t; idx < 1600; idx += 512) {
        Tl[idx] = NEGINF; SHWl[idx] = NEGINF; REl[idx] = NEGINF;
    }
    __syncthreads();
    for (int p = t; p < NPAIR; p += 512) {
        int i = 0, rem = p, len = L_SEQ - 1;
        while (rem >= len) { rem -= len; len--; i++; }
        int j = i + 1 + rem;
        int row = p * 16 + b;
        float tl = tlog[row];
        float re_v = (tl >= 0.f) ? -log1pf(__expf(-tl)) : (tl - log1pf(__expf(tl)));
        float sh_v = (tl <= 0.f) ? -log1pf(__expf(tl)) : (-tl - log1pf(__expf(-tl)));
        float wlp = glog[row] - __logf(rowsum[row]);
        SHWl[i * 40 + j] = sh_v + wlp;
        REl[i * 40 + j] = re_v;
    }
    if (t == 0) {
        int row = NPAIR * 16 + b;           // init cell
        Tl[0 * 40 + 1] = glog[row] - __logf(rowsum[row]);
    }
    if (t >= 1 && t <= 38) Tl[t * 40 + t + 1] = 0.f;
    __syncthreads();
    const int tg = t >> 3, li = t & 7;
    for (int gap = 2; gap <= L_SEQ - 1; gap++) {
        int n_i = L_SEQ - gap;
        float m = NEGINF, s = 0.f;
        int i = tg, j = tg + gap;
        if (tg < n_i) {
            for (int k = i + 1 + li; k < j; k += 8) {
                float v = Tl[i * 40 + k] + Tl[k * 40 + j]
                        + SHWl[i * 40 + k] + REl[k * 40 + j];
                if (v > m) { s = s * __expf(m - v) + 1.f; m = v; }
                else s += __expf(v - m);
            }
        }
#pragma unroll
        for (int off = 1; off < 8; off <<= 1) {
            float mo = __shfl_xor(m, off), so = __shfl_xor(s, off);
            float M = fmaxf(m, mo);
            float sn = 0.f;
            if (m > NEGINF) sn += s * __expf(m - M);
            if (mo > NEGINF) sn += so * __expf(mo - M);
            m = M; s = sn;
        }
        if (tg < n_i && li == 0) Tl[i * 40 + j] = m + __logf(s);
        __syncthreads();
    }
    if (t == 0) out[b] = Tl[39];
}

// ---------------------------------------------------------------------------
extern "C" void kernel_launch(void* const* d_in, const int* in_sizes, int n_in,
                              void* d_out, int out_size, void* d_ws, size_t ws_size,
                              hipStream_t stream) {
    const float* h        = (const float*)d_in[0];
    const int*   sentence = (const int*)d_in[1];
    const float* Wt1      = (const float*)d_in[2];
    const float* bt1      = (const float*)d_in[3];
    const float* Wt2      = (const float*)d_in[4];
    const float* bt2      = (const float*)d_in[5];
    const float* Ww1      = (const float*)d_in[6];
    const float* bw1      = (const float*)d_in[7];
    const float* Ww2      = (const float*)d_in[8];
    const float* bw2      = (const float*)d_in[9];
    float* out = (float*)d_out;

    char* ws = (char*)d_ws;
    size_t off = 0;
    float* UV = (float*)(ws + off);                    off += 4ull * 640 * 256 * 4;
    unsigned short* X = (unsigned short*)(ws + off);   off += (size_t)M_ROWS * 256 * 2;
    unsigned short* WbT = (unsigned short*)(ws + off); off += (size_t)V_PAD * 256 * 2;
    float* WwT = (float*)(ws + off);                   off += (size_t)V_PAD * 256 * 4;
    float* rowsum = (float*)(ws + off);                off += (size_t)M_ROWS * 4;
    float* tlog = (float*)(ws + off);                  off += (size_t)M_ROWS * 4;
    float* glog = (float*)(ws + off);                  off += (size_t)M_ROWS * 4;

    const int zero_blocks = (M_ROWS + 255) / 256;      // 49
    prep_kernel<<<2880 + zero_blocks, 256, 0, stream>>>(
        Ww2, WwT, WbT, h, Wt1, Ww1, UV, rowsum);
    build_rows<<<M_ROWS / 4, 256, 0, stream>>>(UV, sentence, bt1, bw1, Wt2, bt2,
                                               WwT, bw2, X, tlog, glog);
    big_gemm<<<dim3(40, 14), 256, 0, stream>>>(X, WbT, bw2, rowsum);
    dp_kernel<<<16, 512, 0, stream>>>(tlog, glog, rowsum, out);
}

// Round 4
// 243.506 us; speedup vs baseline: 2.0556x; 2.0556x over previous
//
#include <hip/hip_runtime.h>
#include <hip/hip_bf16.h>

#define L_SEQ 40
#define B_SZ  16
#define V_SZ  10000
#define V_PAD 10240
#define NPAIR 780
#define NROWP 784                 // 780 pairs + 1 init row + 3 pad "pairs"
#define M_ROWS (NROWP * B_SZ)     // 12544 rows = 98 strips of 128

typedef __attribute__((ext_vector_type(4))) float f32x4;

// ---------------------------------------------------------------------------
// float -> OCP e4m3fn. Prefer HW cvt; hand-rolled RNE fallback.
// ---------------------------------------------------------------------------
#if __has_builtin(__builtin_amdgcn_cvt_pk_fp8_f32)
__device__ __forceinline__ unsigned int pack4_fp8(float x0, float x1, float x2, float x3) {
    int lo = __builtin_amdgcn_cvt_pk_fp8_f32(x0, x1, 0, false);
    int full = __builtin_amdgcn_cvt_pk_fp8_f32(x2, x3, lo, true);
    return (unsigned int)full;
}
#else
__device__ __forceinline__ unsigned char f2e4m3(float f) {
    unsigned u = __float_as_uint(f);
    unsigned s = (u >> 24) & 0x80u;
    if ((u & 0x7FFFFFFFu) == 0) return (unsigned char)s;
    int E = (int)((u >> 23) & 0xFF) - 127 + 7;
    unsigned m = u & 0x7FFFFFu;
    if (E >= 16) return (unsigned char)(s | 0x7E);
    if (E >= 1) {
        unsigned keep = m >> 20, rest = m & 0xFFFFFu;
        keep += (rest > 0x80000u) || (rest == 0x80000u && (keep & 1));
        if (keep == 8) { keep = 0; E++; if (E >= 16) return (unsigned char)(s | 0x7E); }
        return (unsigned char)(s | (E << 3) | keep);
    }
    int shift = 1 - E;
    if (shift > 10) return (unsigned char)s;
    unsigned full = 0x800000u | m;
    unsigned sh = 20 + shift;
    unsigned keep = full >> sh, rem = full & ((1u << sh) - 1), half = 1u << (sh - 1);
    keep += (rem > half) || (rem == half && (keep & 1));
    if (keep >= 8) return (unsigned char)(s | (1 << 3));
    return (unsigned char)(s | keep);
}
__device__ __forceinline__ unsigned int pack4_fp8(float x0, float x1, float x2, float x3) {
    return (unsigned int)f2e4m3(x0) | ((unsigned int)f2e4m3(x1) << 8)
         | ((unsigned int)f2e4m3(x2) << 16) | ((unsigned int)f2e4m3(x3) << 24);
}
#endif

// ---------------------------------------------------------------------------
// K1: fused prep. [0,2560): transpose Ww2 -> WwT fp32 [10240,256] + WbT fp8;
//     [2560,2880): UV = h @ {Wt1,Ww1} halves; rest: zero rowsum.
// ---------------------------------------------------------------------------
__global__ __launch_bounds__(256) void prep_kernel(
        const float* __restrict__ Ww2, float* __restrict__ WwT,
        unsigned char* __restrict__ WbT,
        const float* __restrict__ h, const float* __restrict__ Wt1,
        const float* __restrict__ Ww1, float* __restrict__ UV,
        float* __restrict__ rowsum) {
    const int bx = blockIdx.x;
    const int t = threadIdx.x;
    __shared__ float tile[32][33];
    __shared__ float hs[8 * 512];
    if (bx < 2560) {
        int v0 = (bx % 320) * 32;
        int k0 = (bx / 320) * 32;
        int tx = t & 31, ty = t >> 5;   // 32 x 8
#pragma unroll
        for (int r = 0; r < 4; r++) {
            int k = k0 + ty + r * 8;
            int v = v0 + tx;
            tile[ty + r * 8][tx] = (v < V_SZ) ? Ww2[k * V_SZ + v] : 0.0f;   // tile[k][v]
        }
        __syncthreads();
        // fp32 transposed write
#pragma unroll
        for (int r = 0; r < 4; r++) {
            int vrow = ty + r * 8;
            WwT[(v0 + vrow) * 256 + (k0 + tx)] = tile[tx][vrow];
        }
        // fp8 write: thread -> (v2, 4 consecutive k)
        int v2 = t >> 3, kq8 = t & 7;
        int kq = kq8 * 4;
        unsigned int pk = pack4_fp8(tile[kq][v2], tile[kq + 1][v2],
                                    tile[kq + 2][v2], tile[kq + 3][v2]);
        ((unsigned int*)WbT)[(v0 + v2) * 64 + (k0 >> 2) + kq8] = pk;
    } else if (bx < 2880) {
        int ub = bx - 2560;
        int which = ub / 80;         // 0:Ut 1:Vt 2:Uw 3:Vw
        int m0 = (ub % 80) * 8;
        const float4* src = (const float4*)(h + (size_t)m0 * 512);
        float4* dst4 = (float4*)hs;
#pragma unroll
        for (int v = 0; v < 4; v++) dst4[v * 256 + t] = src[v * 256 + t];
        __syncthreads();
        const float* W = ((which < 2) ? Wt1 : Ww1) + ((which & 1) ? 512 * 256 : 0);
        float acc[8] = {};
        for (int f = 0; f < 512; f += 4) {
            float w0 = W[(f + 0) * 256 + t];
            float w1 = W[(f + 1) * 256 + t];
            float w2 = W[(f + 2) * 256 + t];
            float w3 = W[(f + 3) * 256 + t];
#pragma unroll
            for (int r = 0; r < 8; r++) {
                acc[r] += hs[r * 512 + f] * w0 + hs[r * 512 + f + 1] * w1
                        + hs[r * 512 + f + 2] * w2 + hs[r * 512 + f + 3] * w3;
            }
        }
        float* dst = UV + ((size_t)which * 640 + m0) * 256;
#pragma unroll
        for (int r = 0; r < 8; r++) dst[r * 256 + t] = acc[r];
    } else {
        int idx = (bx - 2880) * 256 + t;
        if (idx < M_ROWS) rowsum[idx] = 0.0f;
    }
}

// ---------------------------------------------------------------------------
// K2: per (pair,b) row: X = fp8(tanh(Uw[i]+Vw[j]+bw1)); tlog/glog fp32 exact.
// One wave per row; lane covers k = lane*4..+3. p==780 is the init cell.
// ---------------------------------------------------------------------------
__global__ void build_rows(const float* __restrict__ UV,
                           const int* __restrict__ sentence,
                           const float* __restrict__ bt1,
                           const float* __restrict__ bw1,
                           const float* __restrict__ Wt2,
                           const float* __restrict__ bt2,
                           const float* __restrict__ WwT,
                           const float* __restrict__ bw2,
                           unsigned char* __restrict__ X,
                           float* __restrict__ tlog,
                           float* __restrict__ glog) {
    int w = blockIdx.x * 4 + (threadIdx.x >> 6);
    int lane = threadIdx.x & 63;
    int p = w >> 4, b = w & 15;
    int i = 0, j = 0;
    if (p < NPAIR) {
        int rem = p, len = L_SEQ - 1;
        while (rem >= len) { rem -= len; len--; i++; }
        j = i + 1 + rem;
    }
    int j1 = (j + 1 < L_SEQ) ? j + 1 : L_SEQ - 1;
    int tgt = sentence[j1 * B_SZ + b];
    const float4 ut = ((const float4*)(UV + 0 * 640 * 256 + (i * B_SZ + b) * 256))[lane];
    const float4 vt = ((const float4*)(UV + 1 * 640 * 256 + (j * B_SZ + b) * 256))[lane];
    const float4 uw = ((const float4*)(UV + 2 * 640 * 256 + (i * B_SZ + b) * 256))[lane];
    const float4 vw = ((const float4*)(UV + 3 * 640 * 256 + (j * B_SZ + b) * 256))[lane];
    const float4 bt = ((const float4*)bt1)[lane];
    const float4 bw = ((const float4*)bw1)[lane];
    const float4 w2 = ((const float4*)Wt2)[lane];
    const float4 wc = ((const float4*)(WwT + (size_t)tgt * 256))[lane];
    float xt0 = tanhf(ut.x + vt.x + bt.x), xt1 = tanhf(ut.y + vt.y + bt.y);
    float xt2 = tanhf(ut.z + vt.z + bt.z), xt3 = tanhf(ut.w + vt.w + bt.w);
    float xw0 = tanhf(uw.x + vw.x + bw.x), xw1 = tanhf(uw.y + vw.y + bw.y);
    float xw2 = tanhf(uw.z + vw.z + bw.z), xw3 = tanhf(uw.w + vw.w + bw.w);
    ((unsigned int*)X)[w * 64 + lane] = pack4_fp8(xw0, xw1, xw2, xw3);
    float td = xt0 * w2.x + xt1 * w2.y + xt2 * w2.z + xt3 * w2.w;
    float gd = xw0 * wc.x + xw1 * wc.y + xw2 * wc.z + xw3 * wc.w;
#pragma unroll
    for (int off = 32; off >= 1; off >>= 1) {
        td += __shfl_xor(td, off);
        gd += __shfl_xor(gd, off);
    }
    if (lane == 0) {
        tlog[w] = td + bt2[0];
        glog[w] = gd + bw2[tgt];
    }
}

// ---------------------------------------------------------------------------
// K3: fp8 GEMM + fused sum-exp.  logits = X[12544,256] @ WbT^T (+bw2),
// rowsum[row] = sum_col exp(logit).  mfma_f32_16x16x32_fp8_fp8.
// Block (256 thr, 4 waves): 128 rows x 512-col group (8 tiles of 64 cols).
// A strip 32 KB staged once; B tiles 16 KB double-buffered; 64 KB LDS total
// -> 2 blocks/CU. Wave = 64 rows x 32 cols (acc 4x2 f32x4 = 32 AGPR).
// Inner loop: 6 ds_read_b64 + 8 MFMA per k-step, zero global loads.
// XOR-granule swizzle (granule g of row r at LDS slot g^(r&7)) keeps both
// the lane-linear DMA writes and the 16-row strided frag reads ~conflict-free.
// ---------------------------------------------------------------------------
__global__ __launch_bounds__(256) void big_gemm(
        const unsigned char* __restrict__ X,
        const unsigned char* __restrict__ WbT,
        const float* __restrict__ bw2,
        float* __restrict__ rowsum) {
    __shared__ unsigned char As[128 * 256];      // 32 KB
    __shared__ unsigned char Bs[2][64 * 256];    // 2 x 16 KB
    const int t = threadIdx.x;
    const int wid = t >> 6, lane = t & 63;
    const int l15 = lane & 15, l4 = lane >> 4;
    const int rh = wid >> 1;                     // row half (0/1) -> 64 rows
    const int ch = wid & 1;                      // col half (0/1) -> 32 cols
    const int strip = blockIdx.y;                // 128-row strip
    const int cg0 = blockIdx.x * 512;            // column-group base

    // ---- stage A: 128 rows x 256 B, swizzled ----
    {
        const unsigned char* Ag = X + (size_t)strip * 128 * 256;
#pragma unroll
        for (int q = 0; q < 8; q++) {
            int base = q * 4096 + wid * 1024;     // wave-uniform
            int flatL = base + lane * 16;
            int r = flatL >> 8;
            int sg = (flatL >> 4) & 15;
            int cg = sg ^ (r & 7);
            __builtin_amdgcn_global_load_lds(
                (const __attribute__((address_space(1))) unsigned int*)(Ag + (r << 8) + (cg << 4)),
                (__attribute__((address_space(3))) unsigned int*)(As + base),
                16, 0, 0);
        }
    }

    auto dmaB = [&](int buf, int ct) {
        const unsigned char* Bg = WbT + (size_t)(cg0 + ct * 64) * 256;
#pragma unroll
        for (int q = 0; q < 4; q++) {
            int base = q * 4096 + wid * 1024;
            int flatL = base + lane * 16;
            int r = flatL >> 8;
            int sg = (flatL >> 4) & 15;
            int cgx = sg ^ (r & 7);
            __builtin_amdgcn_global_load_lds(
                (const __attribute__((address_space(1))) unsigned int*)(Bg + (r << 8) + (cgx << 4)),
                (__attribute__((address_space(3))) unsigned int*)(&Bs[buf][0] + base),
                16, 0, 0);
        }
    };

    dmaB(0, 0);
    __syncthreads();

    float PS[4][4] = {};
    const int arow0 = rh * 64;
    const int brow0 = ch * 32;

#pragma unroll 1
    for (int ct = 0; ct < 8; ct++) {
        if (ct < 7) dmaB((ct + 1) & 1, ct + 1);
        const unsigned char* Bb = &Bs[ct & 1][0];
        f32x4 acc[4][2] = {};
#pragma unroll
        for (int kk = 0; kk < 8; kk++) {
            const int gA = kk * 2 + (l4 >> 1);     // 16B granule of this k-oct
            const int half = (l4 & 1) << 3;        // low/high 8B
            long a[4], b[2];
#pragma unroll
            for (int mi = 0; mi < 4; mi++) {
                int r = arow0 + mi * 16 + l15;
                a[mi] = *(const long*)(As + r * 256 + ((gA ^ (r & 7)) << 4) + half);
            }
#pragma unroll
            for (int ni = 0; ni < 2; ni++) {
                int r = brow0 + ni * 16 + l15;
                b[ni] = *(const long*)(Bb + r * 256 + ((gA ^ (r & 7)) << 4) + half);
            }
#pragma unroll
            for (int mi = 0; mi < 4; mi++)
#pragma unroll
                for (int ni = 0; ni < 2; ni++)
                    acc[mi][ni] = __builtin_amdgcn_mfma_f32_16x16x32_fp8_fp8(
                        a[mi], b[ni], acc[mi][ni], 0, 0, 0);
        }
        // ---- epilogue: exp(logit + bias), accumulate per-lane partials ----
#pragma unroll
        for (int ni = 0; ni < 2; ni++) {
            int col = cg0 + ct * 64 + brow0 + ni * 16 + l15;
            float bias = (col < V_SZ) ? bw2[col] : -__builtin_inff();
#pragma unroll
            for (int mi = 0; mi < 4; mi++)
#pragma unroll
                for (int r = 0; r < 4; r++)
                    PS[mi][r] += __expf(acc[mi][ni][r] + bias);
        }
        __syncthreads();
    }
    // ---- one butterfly + atomics per wave ----
#pragma unroll
    for (int mi = 0; mi < 4; mi++)
#pragma unroll
        for (int r = 0; r < 4; r++) {
            float v = PS[mi][r];
            v += __shfl_xor(v, 1); v += __shfl_xor(v, 2);
            v += __shfl_xor(v, 4); v += __shfl_xor(v, 8);
            if (l15 == 0)
                atomicAdd(&rowsum[strip * 128 + arow0 + mi * 16 + l4 * 4 + r], v);
        }
}

// ---------------------------------------------------------------------------
// K4: build tables in LDS + CKY DP. 16 blocks (one per batch), 512 thr.
// ---------------------------------------------------------------------------
__global__ __launch_bounds__(512) void dp_kernel(const float* __restrict__ tlog,
                          const float* __restrict__ glog,
                          const float* __restrict__ rowsum,
                          float* __restrict__ out) {
    __shared__ float Tl[1600], SHWl[1600], REl[1600];
    const int t = threadIdx.x;
    const int b = blockIdx.x;
    const float NEGINF = -__builtin_inff();
    for (int idx = t; idx < 1600; idx += 512) {
        Tl[idx] = NEGINF; SHWl[idx] = NEGINF; REl[idx] = NEGINF;
    }
    __syncthreads();
    for (int p = t; p < NPAIR; p += 512) {
        int i = 0, rem = p, len = L_SEQ - 1;
        while (rem >= len) { rem -= len; len--; i++; }
        int j = i + 1 + rem;
        int row = p * 16 + b;
        float tl = tlog[row];
        float re_v = (tl >= 0.f) ? -log1pf(__expf(-tl)) : (tl - log1pf(__expf(tl)));
        float sh_v = (tl <= 0.f) ? -log1pf(__expf(tl)) : (-tl - log1pf(__expf(-tl)));
        float wlp = glog[row] - __logf(rowsum[row]);
        SHWl[i * 40 + j] = sh_v + wlp;
        REl[i * 40 + j] = re_v;
    }
    if (t == 0) {
        int row = NPAIR * 16 + b;           // init cell
        Tl[0 * 40 + 1] = glog[row] - __logf(rowsum[row]);
    }
    if (t >= 1 && t <= 38) Tl[t * 40 + t + 1] = 0.f;
    __syncthreads();
    const int tg = t >> 3, li = t & 7;
    for (int gap = 2; gap <= L_SEQ - 1; gap++) {
        int n_i = L_SEQ - gap;
        float m = NEGINF, s = 0.f;
        int i = tg, j = tg + gap;
        if (tg < n_i) {
            for (int k = i + 1 + li; k < j; k += 8) {
                float v = Tl[i * 40 + k] + Tl[k * 40 + j]
                        + SHWl[i * 40 + k] + REl[k * 40 + j];
                if (v > m) { s = s * __expf(m - v) + 1.f; m = v; }
                else s += __expf(v - m);
            }
        }
#pragma unroll
        for (int off = 1; off < 8; off <<= 1) {
            float mo = __shfl_xor(m, off), so = __shfl_xor(s, off);
            float M = fmaxf(m, mo);
            float sn = 0.f;
            if (m > NEGINF) sn += s * __expf(m - M);
            if (mo > NEGINF) sn += so * __expf(mo - M);
            m = M; s = sn;
        }
        if (tg < n_i && li == 0) Tl[i * 40 + j] = m + __logf(s);
        __syncthreads();
    }
    if (t == 0) out[b] = Tl[39];
}

// ---------------------------------------------------------------------------
extern "C" void kernel_launch(void* const* d_in, const int* in_sizes, int n_in,
                              void* d_out, int out_size, void* d_ws, size_t ws_size,
                              hipStream_t stream) {
    const float* h        = (const float*)d_in[0];
    const int*   sentence = (const int*)d_in[1];
    const float* Wt1      = (const float*)d_in[2];
    const float* bt1      = (const float*)d_in[3];
    const float* Wt2      = (const float*)d_in[4];
    const float* bt2      = (const float*)d_in[5];
    const float* Ww1      = (const float*)d_in[6];
    const float* bw1      = (const float*)d_in[7];
    const float* Ww2      = (const float*)d_in[8];
    const float* bw2      = (const float*)d_in[9];
    float* out = (float*)d_out;

    char* ws = (char*)d_ws;
    size_t off = 0;
    float* UV = (float*)(ws + off);                    off += 4ull * 640 * 256 * 4;
    unsigned char* X = (unsigned char*)(ws + off);     off += (size_t)M_ROWS * 256;
    unsigned char* WbT = (unsigned char*)(ws + off);   off += (size_t)V_PAD * 256;
    float* WwT = (float*)(ws + off);                   off += (size_t)V_PAD * 256 * 4;
    float* rowsum = (float*)(ws + off);                off += (size_t)M_ROWS * 4;
    float* tlog = (float*)(ws + off);                  off += (size_t)M_ROWS * 4;
    float* glog = (float*)(ws + off);                  off += (size_t)M_ROWS * 4;

    const int zero_blocks = (M_ROWS + 255) / 256;      // 49
    prep_kernel<<<2880 + zero_blocks, 256, 0, stream>>>(
        Ww2, WwT, WbT, h, Wt1, Ww1, UV, rowsum);
    build_rows<<<M_ROWS / 4, 256, 0, stream>>>(UV, sentence, bt1, bw1, Wt2, bt2,
                                               WwT, bw2, X, tlog, glog);
    big_gemm<<<dim3(20, 98), 256, 0, stream>>>(X, WbT, bw2, rowsum);
    dp_kernel<<<16, 512, 0, stream>>>(tlog, glog, rowsum, out);
}

// Round 5
// 230.281 us; speedup vs baseline: 2.1737x; 1.0574x over previous
//
#include <hip/hip_runtime.h>
#include <hip/hip_bf16.h>

#define L_SEQ 40
#define B_SZ  16
#define V_SZ  10000
#define V_PAD 10240
#define NPAIR 780
#define NROWP 784                 // 780 pairs + 1 init row + 3 pad "pairs"
#define M_ROWS (NROWP * B_SZ)     // 12544 rows = 98 strips of 128

typedef __attribute__((ext_vector_type(4))) float f32x4;
typedef __attribute__((ext_vector_type(2))) long lng2;

// ---------------------------------------------------------------------------
// float -> OCP e4m3fn. Prefer HW cvt; hand-rolled RNE fallback.
// ---------------------------------------------------------------------------
#if __has_builtin(__builtin_amdgcn_cvt_pk_fp8_f32)
__device__ __forceinline__ unsigned int pack4_fp8(float x0, float x1, float x2, float x3) {
    int lo = __builtin_amdgcn_cvt_pk_fp8_f32(x0, x1, 0, false);
    int full = __builtin_amdgcn_cvt_pk_fp8_f32(x2, x3, lo, true);
    return (unsigned int)full;
}
#else
__device__ __forceinline__ unsigned char f2e4m3(float f) {
    unsigned u = __float_as_uint(f);
    unsigned s = (u >> 24) & 0x80u;
    if ((u & 0x7FFFFFFFu) == 0) return (unsigned char)s;
    int E = (int)((u >> 23) & 0xFF) - 127 + 7;
    unsigned m = u & 0x7FFFFFu;
    if (E >= 16) return (unsigned char)(s | 0x7E);
    if (E >= 1) {
        unsigned keep = m >> 20, rest = m & 0xFFFFFu;
        keep += (rest > 0x80000u) || (rest == 0x80000u && (keep & 1));
        if (keep == 8) { keep = 0; E++; if (E >= 16) return (unsigned char)(s | 0x7E); }
        return (unsigned char)(s | (E << 3) | keep);
    }
    int shift = 1 - E;
    if (shift > 10) return (unsigned char)s;
    unsigned full = 0x800000u | m;
    unsigned sh = 20 + shift;
    unsigned keep = full >> sh, rem = full & ((1u << sh) - 1), half = 1u << (sh - 1);
    keep += (rem > half) || (rem == half && (keep & 1));
    if (keep >= 8) return (unsigned char)(s | (1 << 3));
    return (unsigned char)(s | keep);
}
__device__ __forceinline__ unsigned int pack4_fp8(float x0, float x1, float x2, float x3) {
    return (unsigned int)f2e4m3(x0) | ((unsigned int)f2e4m3(x1) << 8)
         | ((unsigned int)f2e4m3(x2) << 16) | ((unsigned int)f2e4m3(x3) << 24);
}
#endif

// PK layout: byte k of a 256-B row stored at pos = p*64 + l4*16 + h*8 + j
// where k = (2p+h)*32 + l4*8 + j. A lane's 16 B at (p, l4) covers the two
// k-steps 2p (low 8B) and 2p+1 (high 8B) of its MFMA fragment.

// ---------------------------------------------------------------------------
// K1: fused prep. [0,2560): transpose Ww2 -> WwT fp32 [10240,256] + WbT fp8 PK;
//     [2560,2880): UV = h @ {Wt1,Ww1} halves; rest: zero rowsum.
// ---------------------------------------------------------------------------
__global__ __launch_bounds__(256) void prep_kernel(
        const float* __restrict__ Ww2, float* __restrict__ WwT,
        unsigned char* __restrict__ WbT,
        const float* __restrict__ h, const float* __restrict__ Wt1,
        const float* __restrict__ Ww1, float* __restrict__ UV,
        float* __restrict__ rowsum) {
    const int bx = blockIdx.x;
    const int t = threadIdx.x;
    __shared__ float tile[32][33];
    __shared__ float hs[8 * 512];
    if (bx < 2560) {
        int v0 = (bx % 320) * 32;
        int K8 = bx / 320;           // k-tile index, k0 = K8*32
        int k0 = K8 * 32;
        int tx = t & 31, ty = t >> 5;   // 32 x 8
#pragma unroll
        for (int r = 0; r < 4; r++) {
            int k = k0 + ty + r * 8;
            int v = v0 + tx;
            tile[ty + r * 8][tx] = (v < V_SZ) ? Ww2[k * V_SZ + v] : 0.0f;   // tile[k][v]
        }
        __syncthreads();
        // fp32 transposed write
#pragma unroll
        for (int r = 0; r < 4; r++) {
            int vrow = ty + r * 8;
            WwT[(v0 + vrow) * 256 + (k0 + tx)] = tile[tx][vrow];
        }
        // fp8 PK write: thread -> (col v2, 4 consecutive k)
        int v2 = t >> 3;                 // 0..31
        int kq = 4 * (t & 7);            // local k base 0..28
        unsigned int pk = pack4_fp8(tile[kq][v2], tile[kq + 1][v2],
                                    tile[kq + 2][v2], tile[kq + 3][v2]);
        // PK uint index for global k = K8*32 + kq:
        int idx = (K8 >> 1) * 16 + ((t & 7) >> 1) * 4 + (K8 & 1) * 2 + (t & 1);
        ((unsigned int*)WbT)[(v0 + v2) * 64 + idx] = pk;
    } else if (bx < 2880) {
        int ub = bx - 2560;
        int which = ub / 80;         // 0:Ut 1:Vt 2:Uw 3:Vw
        int m0 = (ub % 80) * 8;
        const float4* src = (const float4*)(h + (size_t)m0 * 512);
        float4* dst4 = (float4*)hs;
#pragma unroll
        for (int v = 0; v < 4; v++) dst4[v * 256 + t] = src[v * 256 + t];
        __syncthreads();
        const float* W = ((which < 2) ? Wt1 : Ww1) + ((which & 1) ? 512 * 256 : 0);
        float acc[8] = {};
        for (int f = 0; f < 512; f += 4) {
            float w0 = W[(f + 0) * 256 + t];
            float w1 = W[(f + 1) * 256 + t];
            float w2 = W[(f + 2) * 256 + t];
            float w3 = W[(f + 3) * 256 + t];
#pragma unroll
            for (int r = 0; r < 8; r++) {
                acc[r] += hs[r * 512 + f] * w0 + hs[r * 512 + f + 1] * w1
                        + hs[r * 512 + f + 2] * w2 + hs[r * 512 + f + 3] * w3;
            }
        }
        float* dst = UV + ((size_t)which * 640 + m0) * 256;
#pragma unroll
        for (int r = 0; r < 8; r++) dst[r * 256 + t] = acc[r];
    } else {
        int idx = (bx - 2880) * 256 + t;
        if (idx < M_ROWS) rowsum[idx] = 0.0f;
    }
}

// ---------------------------------------------------------------------------
// K2: per (pair,b) row: X = fp8(tanh(Uw[i]+Vw[j]+bw1)) in PK order;
//     tlog/glog fp32 exact. One wave per row; p==780 is the init cell.
// ---------------------------------------------------------------------------
__global__ void build_rows(const float* __restrict__ UV,
                           const int* __restrict__ sentence,
                           const float* __restrict__ bt1,
                           const float* __restrict__ bw1,
                           const float* __restrict__ Wt2,
                           const float* __restrict__ bt2,
                           const float* __restrict__ WwT,
                           const float* __restrict__ bw2,
                           unsigned char* __restrict__ X,
                           float* __restrict__ tlog,
                           float* __restrict__ glog) {
    int w = blockIdx.x * 4 + (threadIdx.x >> 6);
    int lane = threadIdx.x & 63;
    int p = w >> 4, b = w & 15;
    int i = 0, j = 0;
    if (p < NPAIR) {
        int rem = p, len = L_SEQ - 1;
        while (rem >= len) { rem -= len; len--; i++; }
        j = i + 1 + rem;
    }
    int j1 = (j + 1 < L_SEQ) ? j + 1 : L_SEQ - 1;
    int tgt = sentence[j1 * B_SZ + b];
    const float4 ut = ((const float4*)(UV + 0 * 640 * 256 + (i * B_SZ + b) * 256))[lane];
    const float4 vt = ((const float4*)(UV + 1 * 640 * 256 + (j * B_SZ + b) * 256))[lane];
    const float4 uw = ((const float4*)(UV + 2 * 640 * 256 + (i * B_SZ + b) * 256))[lane];
    const float4 vw = ((const float4*)(UV + 3 * 640 * 256 + (j * B_SZ + b) * 256))[lane];
    const float4 bt = ((const float4*)bt1)[lane];
    const float4 bw = ((const float4*)bw1)[lane];
    const float4 w2 = ((const float4*)Wt2)[lane];
    const float4 wc = ((const float4*)(WwT + (size_t)tgt * 256))[lane];
    float xt0 = tanhf(ut.x + vt.x + bt.x), xt1 = tanhf(ut.y + vt.y + bt.y);
    float xt2 = tanhf(ut.z + vt.z + bt.z), xt3 = tanhf(ut.w + vt.w + bt.w);
    float xw0 = tanhf(uw.x + vw.x + bw.x), xw1 = tanhf(uw.y + vw.y + bw.y);
    float xw2 = tanhf(uw.z + vw.z + bw.z), xw3 = tanhf(uw.w + vw.w + bw.w);
    // PK uint index for k0 = lane*4:
    int pki = (lane >> 4) * 16 + ((lane >> 1) & 3) * 4 + ((lane >> 3) & 1) * 2 + (lane & 1);
    ((unsigned int*)X)[w * 64 + pki] = pack4_fp8(xw0, xw1, xw2, xw3);
    float td = xt0 * w2.x + xt1 * w2.y + xt2 * w2.z + xt3 * w2.w;
    float gd = xw0 * wc.x + xw1 * wc.y + xw2 * wc.z + xw3 * wc.w;
#pragma unroll
    for (int off = 32; off >= 1; off >>= 1) {
        td += __shfl_xor(td, off);
        gd += __shfl_xor(gd, off);
    }
    if (lane == 0) {
        tlog[w] = td + bt2[0];
        glog[w] = gd + bw2[tgt];
    }
}

// ---------------------------------------------------------------------------
// K3: fp8 GEMM + fused sum-exp, A-in-registers.
// Grid (8 col-groups, 98 row-strips), 4 waves/block (2 row-halves x 2
// col-halves). Wave = 64 rows x 64 cols. The wave's whole A panel
// (64 rows x K=256 fp8) lives in 64 VGPRs, loaded once from global (PK
// layout). K-loop reads ONLY B from LDS: ds_read_b128 per (n-tile, kk-pair)
// = 128 B/MFMA -> MFMA-bound. B tiles (128 cols x 256 B = 32 KB) double-
// buffered (64 KB LDS, 2 blocks/CU) via global_load_lds w=16 with XOR-
// granule swizzle (2-way max = free). 10 iterations of 128 cols; one
// barrier per iteration; exp into per-lane PS regs; one butterfly +
// 16 atomics per wave at kernel end.
// ---------------------------------------------------------------------------
__global__ __launch_bounds__(256, 2) void big_gemm(
        const unsigned char* __restrict__ X,
        const unsigned char* __restrict__ WbT,
        const float* __restrict__ bw2,
        float* __restrict__ rowsum) {
    __shared__ unsigned char Bs[2][128 * 256];   // 2 x 32 KB
    const int t = threadIdx.x;
    const int wid = t >> 6, lane = t & 63;
    const int l15 = lane & 15, l4 = lane >> 4;
    const int rh = wid >> 1, ch = wid & 1;
    const int g = blockIdx.x;                    // col group: 1280 cols
    const int row0 = blockIdx.y * 128 + rh * 64; // wave's 64 rows

    auto dmaB = [&](int buf, int it) {
        const unsigned char* Bg = WbT + (size_t)(g * 1280 + it * 128) * 256;
#pragma unroll
        for (int q = 0; q < 8; q++) {
            int base = (wid * 8 + q) * 1024;     // wave-uniform dest
            int F = base + lane * 16;            // this lane's dest byte
            int cc = F >> 8;                     // dest col within tile
            int s = (F >> 4) & 15;               // dest granule slot
            int srcg = s ^ (cc & 15);            // swizzled source granule
            __builtin_amdgcn_global_load_lds(
                (const __attribute__((address_space(1))) unsigned int*)(Bg + cc * 256 + (srcg << 4)),
                (__attribute__((address_space(3))) unsigned int*)(&Bs[buf][0] + base),
                16, 0, 0);
        }
    };

    dmaB(0, 0);

    // ---- A panel: 64 rows x K=256 in 64 VGPRs (PK layout: direct 16B loads)
    lng2 apan[4][4];
    {
        const unsigned char* Ag = X + (size_t)row0 * 256;
#pragma unroll
        for (int mi = 0; mi < 4; mi++)
#pragma unroll
            for (int p = 0; p < 4; p++)
                apan[mi][p] = *(const lng2*)(Ag + (mi * 16 + l15) * 256 + p * 64 + l4 * 16);
    }
    __syncthreads();   // drains DMA for iter 0 too

    float PS[4][4] = {};

#pragma unroll 1
    for (int it = 0; it < 10; it++) {
        if (it < 9) dmaB((it + 1) & 1, it + 1);
        const unsigned char* Bb = &Bs[it & 1][0];
        f32x4 acc[4][4] = {};
#pragma unroll
        for (int p = 0; p < 4; p++) {
            lng2 b[4];
#pragma unroll
            for (int ni = 0; ni < 4; ni++) {
                int cc = ch * 64 + ni * 16 + l15;
                b[ni] = *(const lng2*)(Bb + cc * 256 + (((p * 4 + l4) ^ (cc & 15)) << 4));
            }
#pragma unroll
            for (int mi = 0; mi < 4; mi++)
#pragma unroll
                for (int ni = 0; ni < 4; ni++) {
                    acc[mi][ni] = __builtin_amdgcn_mfma_f32_16x16x32_fp8_fp8(
                        apan[mi][p].x, b[ni].x, acc[mi][ni], 0, 0, 0);
                    acc[mi][ni] = __builtin_amdgcn_mfma_f32_16x16x32_fp8_fp8(
                        apan[mi][p].y, b[ni].y, acc[mi][ni], 0, 0, 0);
                }
        }
        // ---- epilogue: exp(logit + bias) into per-lane partials ----
#pragma unroll
        for (int ni = 0; ni < 4; ni++) {
            int col = g * 1280 + it * 128 + ch * 64 + ni * 16 + l15;
            float bias = (col < V_SZ) ? bw2[col] : -__builtin_inff();
#pragma unroll
            for (int mi = 0; mi < 4; mi++)
#pragma unroll
                for (int r = 0; r < 4; r++)
                    PS[mi][r] += __expf(acc[mi][ni][r] + bias);
        }
        __syncthreads();
    }
    // ---- one butterfly + atomics per wave ----
#pragma unroll
    for (int mi = 0; mi < 4; mi++)
#pragma unroll
        for (int r = 0; r < 4; r++) {
            float v = PS[mi][r];
            v += __shfl_xor(v, 1); v += __shfl_xor(v, 2);
            v += __shfl_xor(v, 4); v += __shfl_xor(v, 8);
            if (l15 == 0)
                atomicAdd(&rowsum[row0 + mi * 16 + l4 * 4 + r], v);
        }
}

// ---------------------------------------------------------------------------
// K4: build tables in LDS + CKY DP. 16 blocks (one per batch), 1024 thr,
// 16 lanes per (i) cell parallelize the split loop.
// ---------------------------------------------------------------------------
__global__ __launch_bounds__(1024) void dp_kernel(const float* __restrict__ tlog,
                          const float* __restrict__ glog,
                          const float* __restrict__ rowsum,
                          float* __restrict__ out) {
    __shared__ float Tl[1600], SHWl[1600], REl[1600];
    const int t = threadIdx.x;
    const int b = blockIdx.x;
    const float NEGINF = -__builtin_inff();
    for (int idx = t; idx < 1600; idx += 1024) {
        Tl[idx] = NEGINF; SHWl[idx] = NEGINF; REl[idx] = NEGINF;
    }
    __syncthreads();
    for (int p = t; p < NPAIR; p += 1024) {
        int i = 0, rem = p, len = L_SEQ - 1;
        while (rem >= len) { rem -= len; len--; i++; }
        int j = i + 1 + rem;
        int row = p * 16 + b;
        float tl = tlog[row];
        float re_v = (tl >= 0.f) ? -log1pf(__expf(-tl)) : (tl - log1pf(__expf(tl)));
        float sh_v = (tl <= 0.f) ? -log1pf(__expf(tl)) : (-tl - log1pf(__expf(-tl)));
        float wlp = glog[row] - __logf(rowsum[row]);
        SHWl[i * 40 + j] = sh_v + wlp;
        REl[i * 40 + j] = re_v;
    }
    if (t == 0) {
        int row = NPAIR * 16 + b;           // init cell
        Tl[0 * 40 + 1] = glog[row] - __logf(rowsum[row]);
    }
    if (t >= 1 && t <= 38) Tl[t * 40 + t + 1] = 0.f;
    __syncthreads();
    const int tg = t >> 4, li = t & 15;
    for (int gap = 2; gap <= L_SEQ - 1; gap++) {
        int n_i = L_SEQ - gap;
        float m = NEGINF, s = 0.f;
        int i = tg, j = tg + gap;
        if (tg < n_i) {
            for (int k = i + 1 + li; k < j; k += 16) {
                float v = Tl[i * 40 + k] + Tl[k * 40 + j]
                        + SHWl[i * 40 + k] + REl[k * 40 + j];
                if (v > m) { s = s * __expf(m - v) + 1.f; m = v; }
                else s += __expf(v - m);
            }
        }
#pragma unroll
        for (int off = 1; off < 16; off <<= 1) {
            float mo = __shfl_xor(m, off), so = __shfl_xor(s, off);
            float M = fmaxf(m, mo);
            float sn = 0.f;
            if (m > NEGINF) sn += s * __expf(m - M);
            if (mo > NEGINF) sn += so * __expf(mo - M);
            m = M; s = sn;
        }
        if (tg < n_i && li == 0) Tl[i * 40 + j] = m + __logf(s);
        __syncthreads();
    }
    if (t == 0) out[b] = Tl[39];
}

// ---------------------------------------------------------------------------
extern "C" void kernel_launch(void* const* d_in, const int* in_sizes, int n_in,
                              void* d_out, int out_size, void* d_ws, size_t ws_size,
                              hipStream_t stream) {
    const float* h        = (const float*)d_in[0];
    const int*   sentence = (const int*)d_in[1];
    const float* Wt1      = (const float*)d_in[2];
    const float* bt1      = (const float*)d_in[3];
    const float* Wt2      = (const float*)d_in[4];
    const float* bt2      = (const float*)d_in[5];
    const float* Ww1      = (const float*)d_in[6];
    const float* bw1      = (const float*)d_in[7];
    const float* Ww2      = (const float*)d_in[8];
    const float* bw2      = (const float*)d_in[9];
    float* out = (float*)d_out;

    char* ws = (char*)d_ws;
    size_t off = 0;
    float* UV = (float*)(ws + off);                    off += 4ull * 640 * 256 * 4;
    unsigned char* X = (unsigned char*)(ws + off);     off += (size_t)M_ROWS * 256;
    unsigned char* WbT = (unsigned char*)(ws + off);   off += (size_t)V_PAD * 256;
    float* WwT = (float*)(ws + off);                   off += (size_t)V_PAD * 256 * 4;
    float* rowsum = (float*)(ws + off);                off += (size_t)M_ROWS * 4;
    float* tlog = (float*)(ws + off);                  off += (size_t)M_ROWS * 4;
    float* glog = (float*)(ws + off);                  off += (size_t)M_ROWS * 4;

    const int zero_blocks = (M_ROWS + 255) / 256;      // 49
    prep_kernel<<<2880 + zero_blocks, 256, 0, stream>>>(
        Ww2, WwT, WbT, h, Wt1, Ww1, UV, rowsum);
    build_rows<<<M_ROWS / 4, 256, 0, stream>>>(UV, sentence, bt1, bw1, Wt2, bt2,
                                               WwT, bw2, X, tlog, glog);
    big_gemm<<<dim3(8, 98), 256, 0, stream>>>(X, WbT, bw2, rowsum);
    dp_kernel<<<16, 1024, 0, stream>>>(tlog, glog, rowsum, out);
}